// Round 6
// baseline (457.679 us; speedup 1.0000x reference)
//
#include <hip/hip_runtime.h>
#include <hip/hip_bf16.h>

// Attention fwd: B=4 H=16 S=2048 D=128, fp32 in/out, scale = 128^-0.5.
// Prep: V -> VT[bh][d][s] bf16 + K -> bf16 in d_ws (64 MB).
// fattn: 32x32x16 swapped-operand flash attention, BM=256 (4 waves x 64 q-rows)
//   S^T = K·Q^T  (A = K from LDS, B = Q in regs, 2 q-groups share each K read)
//   O^T = V^T·P^T (A = V from LDS shared by 2 q-groups, B = P in regs)
// -> LDS bytes/FLOP halved vs round-5 (the measured bottleneck pipe).
// Keys processed in two 32-key halves to cap live VGPRs (<256, no spill).
// LDS double-buffered (2x35.8KB = 71.7KB, 2 blocks/CU) -> ONE barrier/iter.
// P repack via v_cvt_pk_bf16_f32 + permlane32_swap (T12): no LDS shuffles.
// Defer-max softmax; l kept as per-lane partials, pair-reduced in epilogue.

#define SEQ 2048
#define DH  128
#define NBH 64          // B*H
#define BM  256         // Q rows per block (64 per wave)
#define BN  64          // keys per KV iteration
#define NT  (SEQ / BN)  // 32 KV tiles
#define QK_LD 136       // bf16 elems per row for K tile (128+8): 272B rows
#define VT_LD 72        // (64+8): 144B rows
#define P_LD  72        // fallback kernel only
#define THR 8.0f        // defer-max threshold (exp2 domain): P <= 2^8

typedef __attribute__((ext_vector_type(8))) short short8;
typedef __attribute__((ext_vector_type(4))) float f32x4;
typedef __attribute__((ext_vector_type(16))) float f32x16;
typedef __attribute__((ext_vector_type(2))) unsigned int u32x2;

#if __has_builtin(__builtin_amdgcn_exp2f)
#define EXP2F(x) __builtin_amdgcn_exp2f(x)
#else
#define EXP2F(x) exp2f(x)
#endif

// softmax scale folded with log2(e), pre-applied to Q at load time
#define CS (0.08838834764831845f * 1.44269504088896340736f)

__device__ __forceinline__ unsigned int pk_bf16(float lo, float hi) {
    union { __hip_bfloat162 h; unsigned int u; } cv;
    cv.h = __float22bfloat162_rn(make_float2(lo, hi));   // v_cvt_pk_bf16_f32
    return cv.u;
}

// Build one PV B-frag (16 keys) from 8 fp32 P values held across the lane^32
// pair. dwords: lo-half lanes own {k0k1,k2k3}, hi-half lanes own {k4k5,k6k7}
// of their half; permlane32_swap exchanges the complementary dwords.
__device__ __forceinline__ short8 repack_pf(float a0, float a1, float a2, float a3,
                                            float a4, float a5, float a6, float a7,
                                            int hi) {
    unsigned pq0 = pk_bf16(a0, a1);
    unsigned pq1 = pk_bf16(a2, a3);
    unsigned pq2 = pk_bf16(a4, a5);
    unsigned pq3 = pk_bf16(a6, a7);
    union { short8 s; uint4 u; } cv;
#if __has_builtin(__builtin_amdgcn_permlane32_swap)
    u32x2 r02 = __builtin_amdgcn_permlane32_swap(pq0, pq2, false, false);
    u32x2 r13 = __builtin_amdgcn_permlane32_swap(pq1, pq3, false, false);
    cv.u.x = r02[0]; cv.u.y = r13[0]; cv.u.z = r02[1]; cv.u.w = r13[1];
    (void)hi;
#else
    unsigned px0 = (unsigned)__shfl_xor((int)pq0, 32);
    unsigned px1 = (unsigned)__shfl_xor((int)pq1, 32);
    unsigned px2 = (unsigned)__shfl_xor((int)pq2, 32);
    unsigned px3 = (unsigned)__shfl_xor((int)pq3, 32);
    cv.u.x = hi ? px2 : pq0;
    cv.u.y = hi ? px3 : pq1;
    cv.u.z = hi ? pq2 : px0;
    cv.u.w = hi ? pq3 : px1;
#endif
    return cv.s;
}

// ---- fused prep: V[bh][s][d] f32 -> VT[bh][d][s] bf16 (transpose, full-D
// ---- 64x128 tile per block) and, if DOK, K f32 -> bf16 streaming. ----
template<bool DOK>
__global__ __launch_bounds__(256) void prep_kernel(
        const float* __restrict__ v, unsigned short* __restrict__ vt,
        const float* __restrict__ k, unsigned short* __restrict__ kb) {
    __shared__ float tile[64][129];         // [key][d], +1 pad
    const int bh  = blockIdx.z;
    const int s0  = blockIdx.x * 64;
    const int tid = threadIdx.x;

    if (DOK) {
        const size_t kbase = ((size_t)blockIdx.x + 32 * (size_t)bh) * 8192;
#pragma unroll
        for (int i = 0; i < 8; ++i) {
            size_t idx = kbase + ((size_t)tid + 256 * i) * 4;
            float4 val = *reinterpret_cast<const float4*>(k + idx);
            uint2 pk;
            pk.x = pk_bf16(val.x, val.y);
            pk.y = pk_bf16(val.z, val.w);
            *reinterpret_cast<uint2*>(kb + idx) = pk;
        }
    }

    const float* src = v + ((size_t)bh * SEQ + s0) * DH;
#pragma unroll
    for (int i = 0; i < 8; ++i) {
        int id  = tid + 256 * i;
        int row = id >> 5;                  // 0..63 key
        int c4  = (id & 31) << 2;           // 0..124 d
        float4 val = *reinterpret_cast<const float4*>(src + row * DH + c4);
        tile[row][c4 + 0] = val.x;
        tile[row][c4 + 1] = val.y;
        tile[row][c4 + 2] = val.z;
        tile[row][c4 + 3] = val.w;
    }
    __syncthreads();
    unsigned short* dst = vt + (size_t)bh * DH * SEQ + s0;
#pragma unroll
    for (int i = 0; i < 4; ++i) {
        int id = tid + 256 * i;
        int dd = id >> 3;                   // 0..127 d row
        int kc = (id & 7) << 3;             // key chunk of 8
        uint4 pk;
        unsigned int* pw = reinterpret_cast<unsigned int*>(&pk);
#pragma unroll
        for (int j = 0; j < 4; ++j)
            pw[j] = pk_bf16(tile[kc + 2 * j][dd], tile[kc + 2 * j + 1][dd]);
        *reinterpret_cast<uint4*>(dst + (size_t)dd * SEQ + kc) = pk;
    }
}

// ---- flash attention, 32x32x16 swapped operands, 64 q-rows/wave ----
__global__ __launch_bounds__(256, 2) void fattn_kernel(
        const float* __restrict__ q, const unsigned short* __restrict__ kb,
        const unsigned short* __restrict__ vt, float* __restrict__ out) {
    __shared__ unsigned short Ks[2][BN * QK_LD];   // [key][d], double-buffered
    __shared__ unsigned short Vs[2][DH * VT_LD];   // [d][key], double-buffered

    // XCD swizzle: 512 blocks = 8 XCDs x 64; 8 q-blocks per bh contiguous
    const int wid = ((blockIdx.x & 7) << 6) | (blockIdx.x >> 3);
    const int bh  = wid >> 3;
    const int q0  = (wid & 7) * BM;
    const int tid  = threadIdx.x;
    const int w    = tid >> 6;      // wave 0..3 -> q-rows [64w, 64w+64)
    const int lane = tid & 63;
    const int l31  = lane & 31;
    const int hi   = lane >> 5;

    // ---- Q (2 groups x 1 row/lane) into regs as B-frags, scaled by CS ----
    short8 qb0[8], qb1[8];
    {
        const float* qp0 = q + ((size_t)bh * SEQ + q0 + w * 64 + l31) * DH + hi * 8;
        const float* qp1 = qp0 + 32 * DH;
#pragma unroll
        for (int ks = 0; ks < 8; ++ks) {
            float4 x = *reinterpret_cast<const float4*>(qp0 + 16 * ks);
            float4 y = *reinterpret_cast<const float4*>(qp0 + 16 * ks + 4);
            union { short8 s; uint4 u; } cv;
            cv.u.x = pk_bf16(x.x * CS, x.y * CS);
            cv.u.y = pk_bf16(x.z * CS, x.w * CS);
            cv.u.z = pk_bf16(y.x * CS, y.y * CS);
            cv.u.w = pk_bf16(y.z * CS, y.w * CS);
            qb0[ks] = cv.s;
            x = *reinterpret_cast<const float4*>(qp1 + 16 * ks);
            y = *reinterpret_cast<const float4*>(qp1 + 16 * ks + 4);
            cv.u.x = pk_bf16(x.x * CS, x.y * CS);
            cv.u.y = pk_bf16(x.z * CS, x.w * CS);
            cv.u.z = pk_bf16(y.x * CS, y.y * CS);
            cv.u.w = pk_bf16(y.z * CS, y.w * CS);
            qb1[ks] = cv.s;
        }
    }

    f32x16 o0[4], o1[4];                    // O^T per q-group, 4 d-groups
#pragma unroll
    for (int c = 0; c < 4; ++c)
#pragma unroll
        for (int i = 0; i < 16; ++i) { o0[c][i] = 0.f; o1[c][i] = 0.f; }
    float mA = -1e30f, mB = -1e30f;         // per-lane running max (own q-row)
    float lsA = 0.f, lsB = 0.f;             // per-lane PARTIAL sums

    const unsigned short* kbp  = kb + (size_t)bh * SEQ * DH;
    const unsigned short* vptr = vt + (size_t)bh * DH * SEQ;

    // ---- staging: sync load->write (dbuf makes it race-free, 1 barrier/iter)
    auto stage = [&](int k0s, int b) {
#pragma unroll
        for (int i = 0; i < 4; ++i) {
            int id = tid + 256 * i;
            int row = id >> 4;              // 0..63 key
            int c   = (id & 15) << 3;       // 0..120 d
            *reinterpret_cast<uint4*>(&Ks[b][row * QK_LD + c]) =
                *reinterpret_cast<const uint4*>(kbp + (size_t)(k0s + row) * DH + c);
        }
#pragma unroll
        for (int i = 0; i < 4; ++i) {
            int id = tid + 256 * i;
            int dd = id >> 3;               // 0..127 d
            int kc = (id & 7) << 3;         // 0..56 key
            *reinterpret_cast<uint4*>(&Vs[b][dd * VT_LD + kc]) =
                *reinterpret_cast<const uint4*>(vptr + (size_t)dd * SEQ + k0s + kc);
        }
    };

    stage(0, 0);
    __syncthreads();
    int cur = 0;

    for (int kt = 0; kt < NT; ++kt) {
        if (kt + 1 < NT) stage((kt + 1) * BN, cur ^ 1);   // other buffer: no barrier

        const unsigned short* KsA = &Ks[cur][l31 * QK_LD + hi * 8];
        const unsigned short* VsA = &Vs[cur][l31 * VT_LD + hi * 8];

        // ---- two 32-key halves: caps live regs (one S-pair at a time) ----
#pragma unroll
        for (int h = 0; h < 2; ++h) {
            f32x16 sA, sB;
#pragma unroll
            for (int i = 0; i < 16; ++i) { sA[i] = 0.f; sB[i] = 0.f; }
            const unsigned short* KA = KsA + h * 32 * QK_LD;
            __builtin_amdgcn_s_setprio(1);
#pragma unroll
            for (int ks = 0; ks < 8; ++ks) {
                short8 a = *reinterpret_cast<const short8*>(KA + 16 * ks);
                sA = __builtin_amdgcn_mfma_f32_32x32x16_bf16(a, qb0[ks], sA, 0, 0, 0);
                sB = __builtin_amdgcn_mfma_f32_32x32x16_bf16(a, qb1[ks], sB, 0, 0, 0);
            }
            __builtin_amdgcn_s_setprio(0);

            // ---- defer-max online softmax (per q-group) ----
            float mxA = sA[0], mxB = sB[0];
#pragma unroll
            for (int i = 1; i < 16; ++i) {
                mxA = fmaxf(mxA, sA[i]);
                mxB = fmaxf(mxB, sB[i]);
            }
            mxA = fmaxf(mxA, __shfl_xor(mxA, 32));
            mxB = fmaxf(mxB, __shfl_xor(mxB, 32));
            if (__any(fmaxf(mxA - mA, mxB - mB) > THR)) {
                float mnA = fmaxf(mA, mxA), mnB = fmaxf(mB, mxB);
                float alA = EXP2F(mA - mnA), alB = EXP2F(mB - mnB);
                mA = mnA; mB = mnB; lsA *= alA; lsB *= alB;
#pragma unroll
                for (int c = 0; c < 4; ++c)
#pragma unroll
                    for (int i = 0; i < 16; ++i) { o0[c][i] *= alA; o1[c][i] *= alB; }
            }
#pragma unroll
            for (int i = 0; i < 16; ++i) {
                sA[i] = EXP2F(sA[i] - mA);
                sB[i] = EXP2F(sB[i] - mB);
            }
            float la = 0.f, lb = 0.f;
#pragma unroll
            for (int i = 0; i < 16; ++i) { la += sA[i]; lb += sB[i]; }
            lsA += la; lsB += lb;

            // ---- repack P -> B-frags (cvt_pk + permlane32_swap) ----
            short8 pfA0 = repack_pf(sA[0], sA[1], sA[2],  sA[3],  sA[4],  sA[5],  sA[6],  sA[7],  hi);
            short8 pfA1 = repack_pf(sA[8], sA[9], sA[10], sA[11], sA[12], sA[13], sA[14], sA[15], hi);
            short8 pfB0 = repack_pf(sB[0], sB[1], sB[2],  sB[3],  sB[4],  sB[5],  sB[6],  sB[7],  hi);
            short8 pfB1 = repack_pf(sB[8], sB[9], sB[10], sB[11], sB[12], sB[13], sB[14], sB[15], hi);

            // ---- O^T += V^T . P^T : each V read feeds both q-groups ----
            __builtin_amdgcn_s_setprio(1);
#pragma unroll
            for (int c = 0; c < 4; ++c) {
                const unsigned short* VA = VsA + c * 32 * VT_LD + h * 32;
                short8 v0 = *reinterpret_cast<const short8*>(VA);
                short8 v1 = *reinterpret_cast<const short8*>(VA + 16);
                o0[c] = __builtin_amdgcn_mfma_f32_32x32x16_bf16(v0, pfA0, o0[c], 0, 0, 0);
                o0[c] = __builtin_amdgcn_mfma_f32_32x32x16_bf16(v1, pfA1, o0[c], 0, 0, 0);
                o1[c] = __builtin_amdgcn_mfma_f32_32x32x16_bf16(v0, pfB0, o1[c], 0, 0, 0);
                o1[c] = __builtin_amdgcn_mfma_f32_32x32x16_bf16(v1, pfB1, o1[c], 0, 0, 0);
            }
            __builtin_amdgcn_s_setprio(0);
        }

        __syncthreads();                    // staging done + all reads done
        cur ^= 1;
    }

    // ---- epilogue: pair-reduce l, normalize, store fp32 ----
    lsA += __shfl_xor(lsA, 32);
    lsB += __shfl_xor(lsB, 32);
    float invA = 1.0f / lsA;
    float invB = 1.0f / lsB;
    float* ob0 = out + ((size_t)bh * SEQ + q0 + w * 64 + l31) * DH + 4 * hi;
    float* ob1 = ob0 + (size_t)32 * DH;
#pragma unroll
    for (int c = 0; c < 4; ++c) {
#pragma unroll
        for (int u = 0; u < 4; ++u) {
            float4 st;
            st.x = o0[c][4*u+0] * invA; st.y = o0[c][4*u+1] * invA;
            st.z = o0[c][4*u+2] * invA; st.w = o0[c][4*u+3] * invA;
            *reinterpret_cast<float4*>(ob0 + 32 * c + 8 * u) = st;
            st.x = o1[c][4*u+0] * invB; st.y = o1[c][4*u+1] * invB;
            st.z = o1[c][4*u+2] * invB; st.w = o1[c][4*u+3] * invB;
            *reinterpret_cast<float4*>(ob1 + 32 * c + 8 * u) = st;
        }
    }
}

// ---- fallback (ws < 64 MB): round-2-verified 16x16 kernel, in-loop K cvt ----
__global__ __launch_bounds__(256, 3) void fattn_fallback(
        const float* __restrict__ q, const float* __restrict__ kf,
        const unsigned short* __restrict__ vt, float* __restrict__ out) {
    __shared__ unsigned short Ks[64 * QK_LD];
    __shared__ unsigned short Vs[DH * VT_LD];
    __shared__ unsigned short Ps[64 * P_LD];

    const int wid = ((blockIdx.x & 7) << 8) | (blockIdx.x >> 3);
    const int bh  = wid >> 5;
    const int q0  = (wid & 31) * 64;
    const int tid  = threadIdx.x;
    const int w    = tid >> 6;
    const int lane = tid & 63;
    const int l15  = lane & 15;
    const int quad = lane >> 4;

    short8 qf[4];
    {
        const float* qptr = q + ((size_t)bh * SEQ + q0 + w * 16 + l15) * DH + quad * 8;
#pragma unroll
        for (int kk = 0; kk < 4; ++kk) {
            float4 x = *reinterpret_cast<const float4*>(qptr + kk * 32);
            float4 y = *reinterpret_cast<const float4*>(qptr + kk * 32 + 4);
            union { short8 s; uint4 u; } cv;
            cv.u.x = pk_bf16(x.x * CS, x.y * CS);
            cv.u.y = pk_bf16(x.z * CS, x.w * CS);
            cv.u.z = pk_bf16(y.x * CS, y.y * CS);
            cv.u.w = pk_bf16(y.z * CS, y.w * CS);
            qf[kk] = cv.s;
        }
    }

    f32x4 o[8];
#pragma unroll
    for (int t = 0; t < 8; ++t) o[t] = (f32x4){0.f, 0.f, 0.f, 0.f};
    float mrow[4] = {-1e30f, -1e30f, -1e30f, -1e30f};
    float lrow[4] = {0.f, 0.f, 0.f, 0.f};

    const float*          kfp  = kf + (size_t)bh * SEQ * DH;
    const unsigned short* vptr = vt + (size_t)bh * DH * SEQ;

    unsigned int* Ps32 = reinterpret_cast<unsigned int*>(Ps);
    const int prow_base = w * 16 + quad * 4;
    const int pdw = (l15 & 1) ? (8 + (l15 >> 1)) : (l15 >> 1);

    for (int kt = 0; kt < NT; ++kt) {
        const int k0 = kt * BN;
#pragma unroll
        for (int i = 0; i < 8; ++i) {
            int id  = tid + 256 * i;
            int row = id >> 5;
            int c4  = (id & 31) << 2;
            float4 val = *reinterpret_cast<const float4*>(kfp + (size_t)(k0 + row) * DH + c4);
            uint2 pk;
            pk.x = pk_bf16(val.x, val.y);
            pk.y = pk_bf16(val.z, val.w);
            *reinterpret_cast<uint2*>(&Ks[row * QK_LD + c4]) = pk;
        }
#pragma unroll
        for (int i = 0; i < 4; ++i) {
            int id = tid + 256 * i;
            int dd = id >> 3;
            int kc = (id & 7) << 3;
            *reinterpret_cast<uint4*>(&Vs[dd * VT_LD + kc]) =
                *reinterpret_cast<const uint4*>(vptr + (size_t)dd * SEQ + k0 + kc);
        }
        __syncthreads();

        f32x4 acc[4];
#pragma unroll
        for (int t = 0; t < 4; ++t) acc[t] = (f32x4){0.f, 0.f, 0.f, 0.f};
#pragma unroll
        for (int kk = 0; kk < 4; ++kk) {
            const int koff = kk * 32 + quad * 8;
#pragma unroll
            for (int t = 0; t < 4; ++t) {
                short8 b = *reinterpret_cast<const short8*>(&Ks[(t * 16 + l15) * QK_LD + koff]);
                acc[t] = __builtin_amdgcn_mfma_f32_16x16x32_bf16(qf[kk], b, acc[t], 0, 0, 0);
            }
        }

        float lm[4];
#pragma unroll
        for (int r = 0; r < 4; ++r)
            lm[r] = fmaxf(fmaxf(acc[0][r], acc[1][r]), fmaxf(acc[2][r], acc[3][r]));
        float need = fmaxf(fmaxf(lm[0] - mrow[0], lm[1] - mrow[1]),
                           fmaxf(lm[2] - mrow[2], lm[3] - mrow[3]));
        if (__any(need > THR)) {
#pragma unroll
            for (int r = 0; r < 4; ++r) {
                float mx = lm[r];
#pragma unroll
                for (int off = 1; off < 16; off <<= 1)
                    mx = fmaxf(mx, __shfl_xor(mx, off));
                float mnew  = fmaxf(mrow[r], mx);
                float alpha = EXP2F(mrow[r] - mnew);
                mrow[r] = mnew;
                lrow[r] *= alpha;
#pragma unroll
                for (int t = 0; t < 8; ++t) o[t][r] *= alpha;
            }
        }

#pragma unroll
        for (int r = 0; r < 4; ++r) {
            float p0 = EXP2F(acc[0][r] - mrow[r]);
            float p1 = EXP2F(acc[1][r] - mrow[r]);
            float p2 = EXP2F(acc[2][r] - mrow[r]);
            float p3 = EXP2F(acc[3][r] - mrow[r]);
            lrow[r] += (p0 + p1) + (p2 + p3);
            unsigned int a01 = pk_bf16(p0, p1);
            unsigned int a23 = pk_bf16(p2, p3);
            unsigned int s01 = __shfl_xor((int)a01, 1);
            unsigned int s23 = __shfl_xor((int)a23, 1);
            unsigned int w0, w1;
            if (l15 & 1) {
                w0 = (s01 >> 16) | (a01 & 0xffff0000u);
                w1 = (s23 >> 16) | (a23 & 0xffff0000u);
            } else {
                w0 = (a01 & 0xffffu) | (s01 << 16);
                w1 = (a23 & 0xffffu) | (s23 << 16);
            }
            const int dw = (prow_base + r) * (P_LD / 2) + pdw;
            Ps32[dw]      = w0;
            Ps32[dw + 16] = w1;
        }

#pragma unroll
        for (int kk = 0; kk < 2; ++kk) {
            const int koff = kk * 32 + quad * 8;
            short8 a = *reinterpret_cast<const short8*>(&Ps[(w * 16 + l15) * P_LD + koff]);
#pragma unroll
            for (int t = 0; t < 8; ++t) {
                short8 b = *reinterpret_cast<const short8*>(&Vs[(t * 16 + l15) * VT_LD + koff]);
                o[t] = __builtin_amdgcn_mfma_f32_16x16x32_bf16(a, b, o[t], 0, 0, 0);
            }
        }
        __syncthreads();
    }

#pragma unroll
    for (int r = 0; r < 4; ++r) {
#pragma unroll
        for (int off = 1; off < 16; off <<= 1)
            lrow[r] += __shfl_xor(lrow[r], off);
    }
    float* obase = out + ((size_t)bh * SEQ + q0) * DH;
#pragma unroll
    for (int r = 0; r < 4; ++r) {
        float inv = 1.0f / lrow[r];
        int row = w * 16 + quad * 4 + r;
#pragma unroll
        for (int t = 0; t < 8; ++t)
            obase[(size_t)row * DH + t * 16 + l15] = o[t][r] * inv;
    }
}

extern "C" void kernel_launch(void* const* d_in, const int* in_sizes, int n_in,
                              void* d_out, int out_size, void* d_ws, size_t ws_size,
                              hipStream_t stream) {
    const float* q = (const float*)d_in[0];
    const float* k = (const float*)d_in[1];
    const float* v = (const float*)d_in[2];
    float* out = (float*)d_out;
    unsigned short* vt = (unsigned short*)d_ws;                   // 32 MB

    const size_t vt_elems = (size_t)NBH * SEQ * DH;               // 16M shorts
    if (ws_size >= 2 * vt_elems * sizeof(unsigned short)) {
        unsigned short* kbuf = vt + vt_elems;
        prep_kernel<true><<<dim3(SEQ / 64, 1, NBH), dim3(256), 0, stream>>>(v, vt, k, kbuf);
        fattn_kernel<<<dim3((SEQ / BM) * NBH), dim3(256), 0, stream>>>(q, kbuf, vt, out);
    } else {
        prep_kernel<false><<<dim3(SEQ / 64, 1, NBH), dim3(256), 0, stream>>>(v, vt, nullptr, nullptr);
        fattn_fallback<<<dim3((SEQ / 64) * NBH), dim3(256), 0, stream>>>(q, k, vt, out);
    }
}

// Round 7
// 352.266 us; speedup vs baseline: 1.2992x; 1.2992x over previous
//
#include <hip/hip_runtime.h>
#include <hip/hip_bf16.h>

// Attention fwd: B=4 H=16 S=2048 D=128, fp32 in/out, scale = 128^-0.5.
// Prep: V -> VT[bh][d][s] bf16 + K -> bf16 in d_ws (64 MB).
// fattn: 32x32x16 swapped-operand flash attention, BM=128 (4 waves x 32 q-rows)
//   S^T = K·Q^T  (A = K from LDS, B = Q in regs)
//   O^T = V^T·P^T (A = V from LDS, B = P repacked in regs)
// Round-7 edits vs the 204us round-5 kernel (same register pressure):
//  - LDS double-buffered (2x35.8KB = 71.7KB, 2 blocks/CU) -> ONE barrier/iter
//    (write tile kt+1 into buf cur^1 BEFORE the barrier; nobody reads it yet)
//  - T14 named-scalar global loads issue at TOP of iter -> latency spans
//    QK+softmax+PV, vmcnt drain at WRITE_TILE is free.
// P repack via v_cvt_pk_bf16_f32 + permlane32_swap (T12). Defer-max softmax;
// l kept as per-lane partials, pair-reduced in epilogue. BM=256 is dead:
// 128 acc AGPRs + ~140 live VGPRs > 256 unified budget -> spills (round 6).

#define SEQ 2048
#define DH  128
#define NBH 64          // B*H
#define BM  128         // Q rows per block (32 per wave)
#define BN  64          // keys per KV iteration
#define NT  (SEQ / BN)  // 32 KV tiles
#define QK_LD 136       // bf16 elems per row for K tile (128+8): 272B rows
#define VT_LD 72        // (64+8): 144B rows
#define P_LD  72        // fallback kernel only
#define THR 8.0f        // defer-max threshold (exp2 domain): P <= 2^8

typedef __attribute__((ext_vector_type(8))) short short8;
typedef __attribute__((ext_vector_type(4))) float f32x4;
typedef __attribute__((ext_vector_type(16))) float f32x16;
typedef __attribute__((ext_vector_type(2))) unsigned int u32x2;

#if __has_builtin(__builtin_amdgcn_exp2f)
#define EXP2F(x) __builtin_amdgcn_exp2f(x)
#else
#define EXP2F(x) exp2f(x)
#endif

// softmax scale folded with log2(e), pre-applied to Q at load time
#define CS (0.08838834764831845f * 1.44269504088896340736f)

__device__ __forceinline__ unsigned int pk_bf16(float lo, float hi) {
    union { __hip_bfloat162 h; unsigned int u; } cv;
    cv.h = __float22bfloat162_rn(make_float2(lo, hi));   // v_cvt_pk_bf16_f32
    return cv.u;
}

// Build one PV B-frag (16 keys) from 8 fp32 P values held across the lane^32
// pair. permlane32_swap exchanges the complementary dwords.
__device__ __forceinline__ short8 repack_pf(float a0, float a1, float a2, float a3,
                                            float a4, float a5, float a6, float a7,
                                            int hi) {
    unsigned pq0 = pk_bf16(a0, a1);
    unsigned pq1 = pk_bf16(a2, a3);
    unsigned pq2 = pk_bf16(a4, a5);
    unsigned pq3 = pk_bf16(a6, a7);
    union { short8 s; uint4 u; } cv;
#if __has_builtin(__builtin_amdgcn_permlane32_swap)
    u32x2 r02 = __builtin_amdgcn_permlane32_swap(pq0, pq2, false, false);
    u32x2 r13 = __builtin_amdgcn_permlane32_swap(pq1, pq3, false, false);
    cv.u.x = r02[0]; cv.u.y = r13[0]; cv.u.z = r02[1]; cv.u.w = r13[1];
    (void)hi;
#else
    unsigned px0 = (unsigned)__shfl_xor((int)pq0, 32);
    unsigned px1 = (unsigned)__shfl_xor((int)pq1, 32);
    unsigned px2 = (unsigned)__shfl_xor((int)pq2, 32);
    unsigned px3 = (unsigned)__shfl_xor((int)pq3, 32);
    cv.u.x = hi ? px2 : pq0;
    cv.u.y = hi ? px3 : pq1;
    cv.u.z = hi ? pq2 : px0;
    cv.u.w = hi ? pq3 : px1;
#endif
    return cv.s;
}

// ---- fused prep: V[bh][s][d] f32 -> VT[bh][d][s] bf16 (transpose, full-D
// ---- 64x128 tile per block) and, if DOK, K f32 -> bf16 streaming. ----
template<bool DOK>
__global__ __launch_bounds__(256) void prep_kernel(
        const float* __restrict__ v, unsigned short* __restrict__ vt,
        const float* __restrict__ k, unsigned short* __restrict__ kb) {
    __shared__ float tile[64][129];         // [key][d], +1 pad
    const int bh  = blockIdx.z;
    const int s0  = blockIdx.x * 64;
    const int tid = threadIdx.x;

    if (DOK) {
        const size_t kbase = ((size_t)blockIdx.x + 32 * (size_t)bh) * 8192;
#pragma unroll
        for (int i = 0; i < 8; ++i) {
            size_t idx = kbase + ((size_t)tid + 256 * i) * 4;
            float4 val = *reinterpret_cast<const float4*>(k + idx);
            uint2 pk;
            pk.x = pk_bf16(val.x, val.y);
            pk.y = pk_bf16(val.z, val.w);
            *reinterpret_cast<uint2*>(kb + idx) = pk;
        }
    }

    const float* src = v + ((size_t)bh * SEQ + s0) * DH;
#pragma unroll
    for (int i = 0; i < 8; ++i) {
        int id  = tid + 256 * i;
        int row = id >> 5;                  // 0..63 key
        int c4  = (id & 31) << 2;           // 0..124 d
        float4 val = *reinterpret_cast<const float4*>(src + row * DH + c4);
        tile[row][c4 + 0] = val.x;
        tile[row][c4 + 1] = val.y;
        tile[row][c4 + 2] = val.z;
        tile[row][c4 + 3] = val.w;
    }
    __syncthreads();
    unsigned short* dst = vt + (size_t)bh * DH * SEQ + s0;
#pragma unroll
    for (int i = 0; i < 4; ++i) {
        int id = tid + 256 * i;
        int dd = id >> 3;                   // 0..127 d row
        int kc = (id & 7) << 3;             // key chunk of 8
        uint4 pk;
        unsigned int* pw = reinterpret_cast<unsigned int*>(&pk);
#pragma unroll
        for (int j = 0; j < 4; ++j)
            pw[j] = pk_bf16(tile[kc + 2 * j][dd], tile[kc + 2 * j + 1][dd]);
        *reinterpret_cast<uint4*>(dst + (size_t)dd * SEQ + kc) = pk;
    }
}

// ---- flash attention, 32x32x16 swapped operands, dbuf single-barrier ----
__global__ __launch_bounds__(256, 2) void fattn_kernel(
        const float* __restrict__ q, const unsigned short* __restrict__ kb,
        const unsigned short* __restrict__ vt, float* __restrict__ out) {
    __shared__ unsigned short Ks[2][BN * QK_LD];   // [key][d], double-buffered
    __shared__ unsigned short Vs[2][DH * VT_LD];   // [d][key], double-buffered

    // XCD swizzle: 1024 blocks = 8 XCDs x 128; 16 q-blocks per bh contiguous
    const int wid = ((blockIdx.x & 7) << 7) | (blockIdx.x >> 3);
    const int bh  = wid >> 4;
    const int q0  = (wid & 15) * BM;
    const int tid  = threadIdx.x;
    const int w    = tid >> 6;      // wave 0..3 -> q-rows [32w, 32w+32)
    const int lane = tid & 63;
    const int l31  = lane & 31;
    const int hi   = lane >> 5;

    // ---- Q (one row per lane: q0 + 32w + l31) into regs as B-frags ----
    short8 qb[8];
    {
        const float* qptr = q + ((size_t)bh * SEQ + q0 + w * 32 + l31) * DH + hi * 8;
#pragma unroll
        for (int ks = 0; ks < 8; ++ks) {
            float4 x = *reinterpret_cast<const float4*>(qptr + 16 * ks);
            float4 y = *reinterpret_cast<const float4*>(qptr + 16 * ks + 4);
            union { short8 s; uint4 u; } cv;
            cv.u.x = pk_bf16(x.x * CS, x.y * CS);
            cv.u.y = pk_bf16(x.z * CS, x.w * CS);
            cv.u.z = pk_bf16(y.x * CS, y.y * CS);
            cv.u.w = pk_bf16(y.z * CS, y.w * CS);
            qb[ks] = cv.s;
        }
    }

    f32x16 o0, o1, o2, o3;                  // O^T[d=32c+..][qrow=l31]
#pragma unroll
    for (int i = 0; i < 16; ++i) { o0[i] = 0.f; o1[i] = 0.f; o2[i] = 0.f; o3[i] = 0.f; }
    float m = -1e30f, lsum = 0.f;           // per-lane (qrow) stats; pair l<->l^32

    const unsigned short* kbp  = kb + (size_t)bh * SEQ * DH;
    const unsigned short* vptr = vt + (size_t)bh * DH * SEQ;

    // ---- T14 staging: NAMED scalars only (rule #20) ----
    uint4 kr0, kr1, kr2, kr3, vr0, vr1, vr2, vr3;
    const int krow = tid >> 4, kcol = (tid & 15) << 3;
    const int vrow = tid >> 3, vcol = (tid & 7) << 3;
    const unsigned short* kst = kbp + (size_t)krow * DH + kcol;
    const unsigned short* vst = vptr + (size_t)vrow * SEQ + vcol;

#define LOAD_TILE(K0)                                                              \
    do {                                                                           \
        const unsigned short* _kp = kst + (size_t)(K0) * DH;                       \
        kr0 = *reinterpret_cast<const uint4*>(_kp);                                \
        kr1 = *reinterpret_cast<const uint4*>(_kp + 16 * DH);                      \
        kr2 = *reinterpret_cast<const uint4*>(_kp + 32 * DH);                      \
        kr3 = *reinterpret_cast<const uint4*>(_kp + 48 * DH);                      \
        const unsigned short* _vp = vst + (K0);                                    \
        vr0 = *reinterpret_cast<const uint4*>(_vp);                                \
        vr1 = *reinterpret_cast<const uint4*>(_vp + 32 * SEQ);                     \
        vr2 = *reinterpret_cast<const uint4*>(_vp + 64 * SEQ);                     \
        vr3 = *reinterpret_cast<const uint4*>(_vp + 96 * SEQ);                     \
    } while (0)

#define WRITE_TILE(B)                                                              \
    do {                                                                           \
        *reinterpret_cast<uint4*>(&Ks[B][(krow     ) * QK_LD + kcol]) = kr0;       \
        *reinterpret_cast<uint4*>(&Ks[B][(krow + 16) * QK_LD + kcol]) = kr1;       \
        *reinterpret_cast<uint4*>(&Ks[B][(krow + 32) * QK_LD + kcol]) = kr2;       \
        *reinterpret_cast<uint4*>(&Ks[B][(krow + 48) * QK_LD + kcol]) = kr3;       \
        *reinterpret_cast<uint4*>(&Vs[B][(vrow     ) * VT_LD + vcol]) = vr0;       \
        *reinterpret_cast<uint4*>(&Vs[B][(vrow + 32) * VT_LD + vcol]) = vr1;       \
        *reinterpret_cast<uint4*>(&Vs[B][(vrow + 64) * VT_LD + vcol]) = vr2;       \
        *reinterpret_cast<uint4*>(&Vs[B][(vrow + 96) * VT_LD + vcol]) = vr3;       \
    } while (0)

    LOAD_TILE(0);
    WRITE_TILE(0);
    __syncthreads();
    int cur = 0;

    for (int kt = 0; kt < NT; ++kt) {
        // issue next tile's global loads FIRST: latency spans QK+softmax+PV
        if (kt + 1 < NT) LOAD_TILE((kt + 1) * BN);

        const unsigned short* KsA = &Ks[cur][l31 * QK_LD + hi * 8];
        const unsigned short* VsA = &Vs[cur][l31 * VT_LD + hi * 8];

        // ---- S^T = K . Q^T : s0 = keys[0,32), s1 = keys[32,64) ----
        f32x16 s0, s1;
#pragma unroll
        for (int i = 0; i < 16; ++i) { s0[i] = 0.f; s1[i] = 0.f; }
        __builtin_amdgcn_s_setprio(1);
#pragma unroll
        for (int ks = 0; ks < 8; ++ks) {
            short8 a0 = *reinterpret_cast<const short8*>(KsA + 16 * ks);
            short8 a1 = *reinterpret_cast<const short8*>(KsA + 32 * QK_LD + 16 * ks);
            s0 = __builtin_amdgcn_mfma_f32_32x32x16_bf16(a0, qb[ks], s0, 0, 0, 0);
            s1 = __builtin_amdgcn_mfma_f32_32x32x16_bf16(a1, qb[ks], s1, 0, 0, 0);
        }
        __builtin_amdgcn_s_setprio(0);

        // ---- per-lane softmax (row = own qrow; keys split lane<->lane^32) ----
        float mx = s0[0];
#pragma unroll
        for (int i = 1; i < 16; ++i) mx = fmaxf(mx, s0[i]);
#pragma unroll
        for (int i = 0; i < 16; ++i) mx = fmaxf(mx, s1[i]);
        mx = fmaxf(mx, __shfl_xor(mx, 32));     // pair-consistent row max
        if (__any(mx - m > THR)) {
            float mn = fmaxf(m, mx);
            float al = EXP2F(m - mn);
            m = mn; lsum *= al;
#pragma unroll
            for (int i = 0; i < 16; ++i) { o0[i] *= al; o1[i] *= al; o2[i] *= al; o3[i] *= al; }
        }
#pragma unroll
        for (int i = 0; i < 16; ++i) s0[i] = EXP2F(s0[i] - m);
#pragma unroll
        for (int i = 0; i < 16; ++i) s1[i] = EXP2F(s1[i] - m);
        float ls = 0.f;
#pragma unroll
        for (int i = 0; i < 16; ++i) ls += s0[i] + s1[i];
        lsum += ls;

        // ---- repack P -> PV B-frags (cvt_pk + permlane32_swap) ----
        short8 pf0 = repack_pf(s0[0], s0[1], s0[2],  s0[3],  s0[4],  s0[5],  s0[6],  s0[7],  hi);
        short8 pf1 = repack_pf(s0[8], s0[9], s0[10], s0[11], s0[12], s0[13], s0[14], s0[15], hi);
        short8 pf2 = repack_pf(s1[0], s1[1], s1[2],  s1[3],  s1[4],  s1[5],  s1[6],  s1[7],  hi);
        short8 pf3 = repack_pf(s1[8], s1[9], s1[10], s1[11], s1[12], s1[13], s1[14], s1[15], hi);

        // ---- O^T += V^T . P^T ----
        __builtin_amdgcn_s_setprio(1);
#define PV_C(OC, C)                                                                \
        {                                                                          \
            short8 va0 = *reinterpret_cast<const short8*>(VsA + (32*(C)) * VT_LD);      \
            short8 va1 = *reinterpret_cast<const short8*>(VsA + (32*(C)) * VT_LD + 16); \
            short8 va2 = *reinterpret_cast<const short8*>(VsA + (32*(C)) * VT_LD + 32); \
            short8 va3 = *reinterpret_cast<const short8*>(VsA + (32*(C)) * VT_LD + 48); \
            OC = __builtin_amdgcn_mfma_f32_32x32x16_bf16(va0, pf0, OC, 0, 0, 0);   \
            OC = __builtin_amdgcn_mfma_f32_32x32x16_bf16(va1, pf1, OC, 0, 0, 0);   \
            OC = __builtin_amdgcn_mfma_f32_32x32x16_bf16(va2, pf2, OC, 0, 0, 0);   \
            OC = __builtin_amdgcn_mfma_f32_32x32x16_bf16(va3, pf3, OC, 0, 0, 0);   \
        }
        PV_C(o0, 0) PV_C(o1, 1) PV_C(o2, 2) PV_C(o3, 3)
        __builtin_amdgcn_s_setprio(0);

        // write NEXT tile into the OTHER buffer (nobody reads it this iter),
        // then ONE barrier: publishes writes + closes reads of buf[cur]
        if (kt + 1 < NT) WRITE_TILE(cur ^ 1);
        __syncthreads();
        cur ^= 1;
    }

    // ---- epilogue: pair-reduce l, normalize, store fp32 ----
    lsum += __shfl_xor(lsum, 32);
    float inv = 1.0f / lsum;
    float* obase = out + ((size_t)bh * SEQ + q0 + w * 32 + l31) * DH + 4 * hi;
#define STORE_C(OC, C)                                                             \
    {                                                                              \
        _Pragma("unroll")                                                          \
        for (int u = 0; u < 4; ++u) {                                              \
            float4 st;                                                             \
            st.x = OC[4*u+0] * inv; st.y = OC[4*u+1] * inv;                        \
            st.z = OC[4*u+2] * inv; st.w = OC[4*u+3] * inv;                        \
            *reinterpret_cast<float4*>(obase + 32*(C) + 8*u) = st;                 \
        }                                                                          \
    }
    STORE_C(o0, 0) STORE_C(o1, 1) STORE_C(o2, 2) STORE_C(o3, 3)
}

// ---- fallback (ws < 64 MB): round-2-verified 16x16 kernel, in-loop K cvt ----
__global__ __launch_bounds__(256, 3) void fattn_fallback(
        const float* __restrict__ q, const float* __restrict__ kf,
        const unsigned short* __restrict__ vt, float* __restrict__ out) {
    __shared__ unsigned short Ks[64 * QK_LD];
    __shared__ unsigned short Vs[DH * VT_LD];
    __shared__ unsigned short Ps[64 * P_LD];

    const int wid = ((blockIdx.x & 7) << 8) | (blockIdx.x >> 3);
    const int bh  = wid >> 5;
    const int q0  = (wid & 31) * 64;
    const int tid  = threadIdx.x;
    const int w    = tid >> 6;
    const int lane = tid & 63;
    const int l15  = lane & 15;
    const int quad = lane >> 4;

    short8 qf[4];
    {
        const float* qptr = q + ((size_t)bh * SEQ + q0 + w * 16 + l15) * DH + quad * 8;
#pragma unroll
        for (int kk = 0; kk < 4; ++kk) {
            float4 x = *reinterpret_cast<const float4*>(qptr + kk * 32);
            float4 y = *reinterpret_cast<const float4*>(qptr + kk * 32 + 4);
            union { short8 s; uint4 u; } cv;
            cv.u.x = pk_bf16(x.x * CS, x.y * CS);
            cv.u.y = pk_bf16(x.z * CS, x.w * CS);
            cv.u.z = pk_bf16(y.x * CS, y.y * CS);
            cv.u.w = pk_bf16(y.z * CS, y.w * CS);
            qf[kk] = cv.s;
        }
    }

    f32x4 o[8];
#pragma unroll
    for (int t = 0; t < 8; ++t) o[t] = (f32x4){0.f, 0.f, 0.f, 0.f};
    float mrow[4] = {-1e30f, -1e30f, -1e30f, -1e30f};
    float lrow[4] = {0.f, 0.f, 0.f, 0.f};

    const float*          kfp  = kf + (size_t)bh * SEQ * DH;
    const unsigned short* vptr = vt + (size_t)bh * DH * SEQ;

    unsigned int* Ps32 = reinterpret_cast<unsigned int*>(Ps);
    const int prow_base = w * 16 + quad * 4;
    const int pdw = (l15 & 1) ? (8 + (l15 >> 1)) : (l15 >> 1);

    for (int kt = 0; kt < NT; ++kt) {
        const int k0 = kt * BN;
#pragma unroll
        for (int i = 0; i < 8; ++i) {
            int id  = tid + 256 * i;
            int row = id >> 5;
            int c4  = (id & 31) << 2;
            float4 val = *reinterpret_cast<const float4*>(kfp + (size_t)(k0 + row) * DH + c4);
            uint2 pk;
            pk.x = pk_bf16(val.x, val.y);
            pk.y = pk_bf16(val.z, val.w);
            *reinterpret_cast<uint2*>(&Ks[row * QK_LD + c4]) = pk;
        }
#pragma unroll
        for (int i = 0; i < 4; ++i) {
            int id = tid + 256 * i;
            int dd = id >> 3;
            int kc = (id & 7) << 3;
            *reinterpret_cast<uint4*>(&Vs[dd * VT_LD + kc]) =
                *reinterpret_cast<const uint4*>(vptr + (size_t)dd * SEQ + k0 + kc);
        }
        __syncthreads();

        f32x4 acc[4];
#pragma unroll
        for (int t = 0; t < 4; ++t) acc[t] = (f32x4){0.f, 0.f, 0.f, 0.f};
#pragma unroll
        for (int kk = 0; kk < 4; ++kk) {
            const int koff = kk * 32 + quad * 8;
#pragma unroll
            for (int t = 0; t < 4; ++t) {
                short8 b = *reinterpret_cast<const short8*>(&Ks[(t * 16 + l15) * QK_LD + koff]);
                acc[t] = __builtin_amdgcn_mfma_f32_16x16x32_bf16(qf[kk], b, acc[t], 0, 0, 0);
            }
        }

        float lm[4];
#pragma unroll
        for (int r = 0; r < 4; ++r)
            lm[r] = fmaxf(fmaxf(acc[0][r], acc[1][r]), fmaxf(acc[2][r], acc[3][r]));
        float need = fmaxf(fmaxf(lm[0] - mrow[0], lm[1] - mrow[1]),
                           fmaxf(lm[2] - mrow[2], lm[3] - mrow[3]));
        if (__any(need > THR)) {
#pragma unroll
            for (int r = 0; r < 4; ++r) {
                float mx = lm[r];
#pragma unroll
                for (int off = 1; off < 16; off <<= 1)
                    mx = fmaxf(mx, __shfl_xor(mx, off));
                float mnew  = fmaxf(mrow[r], mx);
                float alpha = EXP2F(mrow[r] - mnew);
                mrow[r] = mnew;
                lrow[r] *= alpha;
#pragma unroll
                for (int t = 0; t < 8; ++t) o[t][r] *= alpha;
            }
        }

#pragma unroll
        for (int r = 0; r < 4; ++r) {
            float p0 = EXP2F(acc[0][r] - mrow[r]);
            float p1 = EXP2F(acc[1][r] - mrow[r]);
            float p2 = EXP2F(acc[2][r] - mrow[r]);
            float p3 = EXP2F(acc[3][r] - mrow[r]);
            lrow[r] += (p0 + p1) + (p2 + p3);
            unsigned int a01 = pk_bf16(p0, p1);
            unsigned int a23 = pk_bf16(p2, p3);
            unsigned int s01 = __shfl_xor((int)a01, 1);
            unsigned int s23 = __shfl_xor((int)a23, 1);
            unsigned int w0, w1;
            if (l15 & 1) {
                w0 = (s01 >> 16) | (a01 & 0xffff0000u);
                w1 = (s23 >> 16) | (a23 & 0xffff0000u);
            } else {
                w0 = (a01 & 0xffffu) | (s01 << 16);
                w1 = (a23 & 0xffffu) | (s23 << 16);
            }
            const int dw = (prow_base + r) * (P_LD / 2) + pdw;
            Ps32[dw]      = w0;
            Ps32[dw + 16] = w1;
        }

#pragma unroll
        for (int kk = 0; kk < 2; ++kk) {
            const int koff = kk * 32 + quad * 8;
            short8 a = *reinterpret_cast<const short8*>(&Ps[(w * 16 + l15) * P_LD + koff]);
#pragma unroll
            for (int t = 0; t < 8; ++t) {
                short8 b = *reinterpret_cast<const short8*>(&Vs[(t * 16 + l15) * VT_LD + koff]);
                o[t] = __builtin_amdgcn_mfma_f32_16x16x32_bf16(a, b, o[t], 0, 0, 0);
            }
        }
        __syncthreads();
    }

#pragma unroll
    for (int r = 0; r < 4; ++r) {
#pragma unroll
        for (int off = 1; off < 16; off <<= 1)
            lrow[r] += __shfl_xor(lrow[r], off);
    }
    float* obase = out + ((size_t)bh * SEQ + q0) * DH;
#pragma unroll
    for (int r = 0; r < 4; ++r) {
        float inv = 1.0f / lrow[r];
        int row = w * 16 + quad * 4 + r;
#pragma unroll
        for (int t = 0; t < 8; ++t)
            obase[(size_t)row * DH + t * 16 + l15] = o[t][r] * inv;
    }
}

extern "C" void kernel_launch(void* const* d_in, const int* in_sizes, int n_in,
                              void* d_out, int out_size, void* d_ws, size_t ws_size,
                              hipStream_t stream) {
    const float* q = (const float*)d_in[0];
    const float* k = (const float*)d_in[1];
    const float* v = (const float*)d_in[2];
    float* out = (float*)d_out;
    unsigned short* vt = (unsigned short*)d_ws;                   // 32 MB

    const size_t vt_elems = (size_t)NBH * SEQ * DH;               // 16M shorts
    if (ws_size >= 2 * vt_elems * sizeof(unsigned short)) {
        unsigned short* kbuf = vt + vt_elems;
        prep_kernel<true><<<dim3(SEQ / 64, 1, NBH), dim3(256), 0, stream>>>(v, vt, k, kbuf);
        fattn_kernel<<<dim3((SEQ / BM) * NBH), dim3(256), 0, stream>>>(q, kbuf, vt, out);
    } else {
        prep_kernel<false><<<dim3(SEQ / 64, 1, NBH), dim3(256), 0, stream>>>(v, vt, nullptr, nullptr);
        fattn_fallback<<<dim3((SEQ / 64) * NBH), dim3(256), 0, stream>>>(q, k, vt, out);
    }
}